// Round 4
// baseline (238.268 us; speedup 1.0000x reference)
//
#include <hip/hip_runtime.h>

// Trajectron sliding-window LSTM embed:
//   inputs [T=256, B=128, N=4, D=2] f32
//   his LSTM H=32 over n=3; int LSTM H=8 over n=0; window 64 ending at t
//   out[t,b,:] = [h_his | h_int] @ W_out.T + b_out   -> [256,128,2] f32
//
// Round-16 (in-wave fusion): three structurally different int kernels all
// measured ~90us (R11 LDS, R14 fp16, R15 hi/lo) -> the int path is
// LATENCY-bound at 2 waves/SIMD, not issue-bound. his (103us) is ~2/3
// trans-issue-bound (80 quarter-rate trans/step) with ~1/3 latency bubbles.
// Fix: fuse int INTO the his wave (same (t,bg) -> same 16 chains in both
// mappings!). Int's +35% issue (2 MFMA + 20 trans + 8 bpermute per step)
// slots into his's latency bubbles; the standalone ~90us intm kernel and
// the eInt global roundtrip disappear. Epilogue combines in-register via
// 8 shfl. All per-step math is byte-identical to the verified R15 kernels.
// (R13's BLOCK-level fusion failed because separate int waves compete with
// his waves for the same trans issue port -- in-wave fusion does not.)

typedef float v2f __attribute__((ext_vector_type(2)));
typedef float v4f __attribute__((ext_vector_type(4)));
typedef _Float16 h8v __attribute__((ext_vector_type(8)));

static __device__ __forceinline__ float fexp2(float x) {
    return __builtin_amdgcn_exp2f(x);
}
static __device__ __forceinline__ float frcp(float x) {
    return __builtin_amdgcn_rcpf(x);
}
static __device__ __forceinline__ unsigned short f2h(float f) {
    _Float16 h = (_Float16)f;
    unsigned short u;
    __builtin_memcpy(&u, &h, 2);
    return u;
}
static __device__ __forceinline__ float h2f(unsigned short u) {
    _Float16 h;
    __builtin_memcpy(&h, &u, 2);
    return (float)h;
}

#define LOG2E    1.442695041f
#define TWOLOG2E 2.885390082f

// ws layout (float index unless noted):
//   ushort [8704,8960)  : intWH_lo fp16 permuted residual Whh_int [32][8]
//   [5120,5248) hisBP : fp32 permuted-prescaled bias, index p
//   [5376,5632) hisXP : fp32 permuted-prescaled Wih, 2p+{0,1}
//   ushort [11776,15872): hisWH fp16 permuted-prescaled Whh [128][32]
//   [7936,7968) intBP : fp32 permuted-prescaled int bias, slot s
//   [7968,8032) intXP : fp32 permuted-prescaled int Wih, 2s+{0,1}
//   ushort [16128,16384): intWH_hi fp16 permuted-prescaled Whh_int [32][8]
// his perm p = T*16+n -> orig row r = (T>>1)*32 + 2n + (T&1)
// int perm slot s = T*16+m (m=q*4+r): gate=(4T+(m&3))>>1,
//   unit=2*(m>>2)+(m&1), orig = gate*8+unit
// scale = -log2e (i,f,o rows) / -2log2e (g rows)
__global__ __launch_bounds__(256) void prep_kernel(
    const float* __restrict__ Wih_his, const float* __restrict__ Whh_his,
    const float* __restrict__ bih_his, const float* __restrict__ bhh_his,
    const float* __restrict__ Wih_int, const float* __restrict__ Whh_int,
    const float* __restrict__ bih_int, const float* __restrict__ bhh_int,
    float* __restrict__ ws)
{
    const int i = blockIdx.x * 256 + threadIdx.x;
    if (i < 4832) {
        // legacy regions dropped (nothing reads them)
    } else if (i < 4960) {              // hisBP (permuted bias, fp32)
        const int p = i - 4832;
        const int T = p >> 4, n = p & 15;
        const int gi = T >> 1, u = 2 * n + (T & 1);
        const int r = gi * 32 + u;
        const float s = (gi == 2) ? -TWOLOG2E : -LOG2E;
        ws[5120 + p] = (bih_his[r] + bhh_his[r]) * s;
    } else if (i < 5216) {              // hisXP (permuted Wih, fp32)
        const int e = i - 4960;
        const int p = e >> 1, comp = e & 1;
        const int T = p >> 4, n = p & 15;
        const int gi = T >> 1, u = 2 * n + (T & 1);
        const int r = gi * 32 + u;
        const float s = (gi == 2) ? -TWOLOG2E : -LOG2E;
        ws[5376 + e] = Wih_his[r * 2 + comp] * s;
    } else if (i < 9312) {              // hisWH (permuted Whh, fp16)
        const int e = i - 5216;
        const int p = e >> 5, k = e & 31;
        const int T = p >> 4, n = p & 15;
        const int gi = T >> 1, u = 2 * n + (T & 1);
        const int r = gi * 32 + u;
        const float s = (gi == 2) ? -TWOLOG2E : -LOG2E;
        reinterpret_cast<unsigned short*>(ws)[11776 + e] =
            f2h(Whh_his[r * 32 + k] * s);
    } else if (i < 9344) {              // intBP (permuted int bias, fp32)
        const int s = i - 9312;
        const int T = s >> 4, m = s & 15, r = m & 3;
        const int gate = (4 * T + r) >> 1, unit = 2 * (m >> 2) + (r & 1);
        const int orig = gate * 8 + unit;
        const float sc = (gate == 2) ? -TWOLOG2E : -LOG2E;
        ws[7936 + s] = (bih_int[orig] + bhh_int[orig]) * sc;
    } else if (i < 9408) {              // intXP (permuted int Wih, fp32)
        const int e = i - 9344;
        const int s = e >> 1, comp = e & 1;
        const int T = s >> 4, m = s & 15, r = m & 3;
        const int gate = (4 * T + r) >> 1, unit = 2 * (m >> 2) + (r & 1);
        const int orig = gate * 8 + unit;
        const float sc = (gate == 2) ? -TWOLOG2E : -LOG2E;
        ws[7968 + e] = Wih_int[orig * 2 + comp] * sc;
    } else if (i < 9664) {              // intWH hi+lo (permuted, fp16 [32][8])
        const int e = i - 9408;
        const int s = e >> 3, k = e & 7;
        const int T = s >> 4, m = s & 15, r = m & 3;
        const int gate = (4 * T + r) >> 1, unit = 2 * (m >> 2) + (r & 1);
        const int orig = gate * 8 + unit;
        const float sc = (gate == 2) ? -TWOLOG2E : -LOG2E;
        const float w = Whh_int[orig * 8 + k] * sc;
        const unsigned short hi = f2h(w);
        const unsigned short lo = f2h(w - h2f(hi));
        reinterpret_cast<unsigned short*>(ws)[16128 + e] = hi;
        reinterpret_cast<unsigned short*>(ws)[8704 + e]  = lo;
    }
}

// ---------- fused his+int LSTM: one wave owns 16 chains of both ----------
// his: D[T] (16 gate-rows x 16 chains) = h_his(A) . WhhP_T(B) + xpart(C)
//      8 MFMAs/step; h-transpose via wave-private LDS roundtrip.
// int: D[T] (16 gate-slots x 16 chains) = WhhP_T(A) . h_int(B) + xpart(C)
//      2 MFMAs/step, hi/lo exact split over idle K; B-gather via 8 bpermute.
__global__ __launch_bounds__(64) void fused_kernel(
    const float* __restrict__ inp, const float* __restrict__ ws,
    const float* __restrict__ W_out, const float* __restrict__ b_out,
    float* __restrict__ out)
{
    __shared__ __align__(16) unsigned short hm[2][16][40];  // fp16 h, padded

    const int lane = threadIdx.x;
    const int n    = lane & 15;
    const int quad = lane >> 4;
    const int Wd   = blockIdx.x;               // 0..2047
    const int t    = Wd >> 3;                  // uniform per wave
    const int bg   = Wd & 7;                   // chains bg*16 .. +15
    const int nsteps = (t >= 63) ? 64 : (t + 1);
    const int tau0   = (t >= 63) ? (t - 63) : 0;

    // ---- his setup: B-frags + C-init constants --------------------------
    h8v Bf[8];
    {
        const h8v* wb = reinterpret_cast<const h8v*>(
            reinterpret_cast<const unsigned short*>(ws) + 11776);
#pragma unroll
        for (int T = 0; T < 8; ++T) Bf[T] = wb[(T * 16 + n) * 4 + quad];
    }
    float cb[8], cw0[8], cw1[8];
#pragma unroll
    for (int T = 0; T < 8; ++T) {
        const int p = T * 16 + n;
        cb[T]  = ws[5120 + p];
        cw0[T] = ws[5376 + 2 * p];
        cw1[T] = ws[5376 + 2 * p + 1];
    }

    // ---- int setup: A-frags (hi for quads 0,1; lo for 2,3) + C consts ---
    h8v Ai[2];
    {
        const h8v* wah = reinterpret_cast<const h8v*>(
            reinterpret_cast<const unsigned short*>(ws) + 16128);
        const h8v* wal = reinterpret_cast<const h8v*>(
            reinterpret_cast<const unsigned short*>(ws) + 8704);
#pragma unroll
        for (int T = 0; T < 2; ++T) {
            const h8v vh = wah[T * 16 + n];
            const h8v vl = wal[T * 16 + n];
            Ai[T] = (quad < 2) ? vh : vl;
        }
    }
    float icb[2][4], icw0[2][4], icw1[2][4];
#pragma unroll
    for (int T = 0; T < 2; ++T)
#pragma unroll
        for (int r = 0; r < 4; ++r) {
            const int s = T * 16 + quad * 4 + r;
            icb[T][r]  = ws[7936 + s];
            icw0[T][r] = ws[7968 + 2 * s];
            icw1[T][r] = ws[7968 + 2 * s + 1];
        }

    // ---- x streams ------------------------------------------------------
    const int bbase = bg * 16 + quad * 4;        // his: 4 chains per lane
    const float* xp = inp + tau0 * 1024 + bbase * 8 + 6;
    float2 xc[4];
#pragma unroll
    for (int r = 0; r < 4; ++r)
        xc[r] = *reinterpret_cast<const float2*>(xp + r * 8);
    xp += 1024;

    const int ichain = bg * 16 + n;              // int: chain n
    const float* ixp = inp + tau0 * 1024 + ichain * 8;
    float2 ixv = *reinterpret_cast<const float2*>(ixp);
    ixp += 1024;

    // ---- states ---------------------------------------------------------
    h8v Af = {};                     // his h (A-frag), fp16
    float cs[4][2] = {};             // his cell [chain-reg][unit-pair]
    float h0[4] = {}, h1[4] = {};    // his h fp32 (for projection)
    union BU { unsigned u[4]; h8v h; } bfr;
    bfr.u[0] = bfr.u[1] = bfr.u[2] = bfr.u[3] = 0;   // int h (B-frag)
    float cI0 = 0.f, cI1 = 0.f, ih0 = 0.f, ih1 = 0.f;

#pragma unroll 1
    for (int s = 0; s < nsteps; ++s) {
        // prefetch next x (his 4x float2 + int 1x float2)
        float2 xn[4];
        float2 ixn = make_float2(0.f, 0.f);
        if (s + 1 < nsteps) {               // wave-uniform branch
#pragma unroll
            for (int r = 0; r < 4; ++r)
                xn[r] = *reinterpret_cast<const float2*>(xp + r * 8);
            ixn = *reinterpret_cast<const float2*>(ixp);
        } else {
#pragma unroll
            for (int r = 0; r < 4; ++r) xn[r] = make_float2(0.f, 0.f);
        }
        xp += 1024;
        ixp += 1024;

        // his: 8 MFMAs D[T] = H @ WhhP_T + (Wih x + b)
        v4f D[8];
#pragma unroll
        for (int T = 0; T < 8; ++T) {
            v4f C;
#pragma unroll
            for (int r = 0; r < 4; ++r)
                C[r] = fmaf(cw1[T], xc[r].y, fmaf(cw0[T], xc[r].x, cb[T]));
            D[T] = __builtin_amdgcn_mfma_f32_16x16x32_f16(Af, Bf[T], C, 0, 0, 0);
        }

        // int: 2 MFMAs (hi/lo exact over idle K-range)
        v4f iD0, iD1;
        {
            v4f C0, C1;
#pragma unroll
            for (int r = 0; r < 4; ++r) {
                C0[r] = fmaf(icw1[0][r], ixv.y, fmaf(icw0[0][r], ixv.x, icb[0][r]));
                C1[r] = fmaf(icw1[1][r], ixv.y, fmaf(icw0[1][r], ixv.x, icb[1][r]));
            }
            iD0 = __builtin_amdgcn_mfma_f32_16x16x32_f16(Ai[0], bfr.h, C0, 0, 0, 0);
            iD1 = __builtin_amdgcn_mfma_f32_16x16x32_f16(Ai[1], bfr.h, C1, 0, 0, 0);
        }

        // int activations first (so its bpermutes can issue under his's)
        {
            const float si = frcp(1.f + fexp2(iD0[0]));
            const float sf = frcp(1.f + fexp2(iD0[2]));
            const float tg = fmaf(2.f, frcp(1.f + fexp2(iD1[0])), -1.f);
            const float so = frcp(1.f + fexp2(iD1[2]));
            const float cn = fmaf(sf, cI0, si * tg);
            cI0 = cn;
            ih0 = so * fmaf(-2.f, frcp(1.f + fexp2(TWOLOG2E * cn)), 1.f);
        }
        {
            const float si = frcp(1.f + fexp2(iD0[1]));
            const float sf = frcp(1.f + fexp2(iD0[3]));
            const float tg = fmaf(2.f, frcp(1.f + fexp2(iD1[1])), -1.f);
            const float so = frcp(1.f + fexp2(iD1[3]));
            const float cn = fmaf(sf, cI1, si * tg);
            cI1 = cn;
            ih1 = so * fmaf(-2.f, frcp(1.f + fexp2(TWOLOG2E * cn)), 1.f);
        }

        // his activations: 4 chains x units {2n, 2n+1}
#pragma unroll
        for (int r = 0; r < 4; ++r) {
            {
                const float si = frcp(1.f + fexp2(D[0][r]));
                const float sf = frcp(1.f + fexp2(D[2][r]));
                const float tg = fmaf(2.f, frcp(1.f + fexp2(D[4][r])), -1.f);
                const float so = frcp(1.f + fexp2(D[6][r]));
                const float cn = fmaf(sf, cs[r][0], si * tg);
                cs[r][0] = cn;
                h0[r] = so * fmaf(-2.f, frcp(1.f + fexp2(TWOLOG2E * cn)), 1.f);
            }
            {
                const float si = frcp(1.f + fexp2(D[1][r]));
                const float sf = frcp(1.f + fexp2(D[3][r]));
                const float tg = fmaf(2.f, frcp(1.f + fexp2(D[5][r])), -1.f);
                const float so = frcp(1.f + fexp2(D[7][r]));
                const float cn = fmaf(sf, cs[r][1], si * tg);
                cs[r][1] = cn;
                h1[r] = so * fmaf(-2.f, frcp(1.f + fexp2(TWOLOG2E * cn)), 1.f);
            }
        }

        if (s + 1 < nsteps) {
            // int h -> B-frag: hi + lo residual, gather dword d from lane
            // d*16+n; quads 0,2 take hi, quads 1,3 take lo
            {
                const unsigned short h0h = f2h(ih0), h1h = f2h(ih1);
                const float h0l = ih0 - h2f(h0h);
                const float h1l = ih1 - h2f(h1h);
                const unsigned pkh = ((unsigned)h1h << 16) | h0h;
                const unsigned pkl = ((unsigned)f2h(h1l) << 16) | f2h(h0l);
#pragma unroll
                for (int d = 0; d < 4; ++d) {
                    const unsigned uh = (unsigned)__shfl((int)pkh, d * 16 + n);
                    const unsigned ul = (unsigned)__shfl((int)pkl, d * 16 + n);
                    bfr.u[d] = (quad & 1) ? ul : uh;
                }
            }
            // his h -> A-frag via wave-private LDS transpose
            const int bfi = s & 1;
#pragma unroll
            for (int r = 0; r < 4; ++r) {
                const unsigned pk =
                    ((unsigned)f2h(h1[r]) << 16) | f2h(h0[r]);
                *reinterpret_cast<unsigned*>(&hm[bfi][quad * 4 + r][2 * n]) = pk;
            }
            __builtin_amdgcn_wave_barrier();
            asm volatile("s_waitcnt lgkmcnt(0)" ::: "memory");
            __builtin_amdgcn_wave_barrier();
            Af = *reinterpret_cast<const h8v*>(&hm[bfi][n][quad * 8]);
        }

#pragma unroll
        for (int r = 0; r < 4; ++r) xc[r] = xn[r];
        ixv = ixn;
    }

    // ---- epilogue -------------------------------------------------------
    // int projection: lane(quad,n) has units {2quad,2quad+1} of chain n;
    // reduce over quad -> every lane holds chain n's int contribution
    float ie0, ie1;
    {
        const float wo0a = W_out[32 + 2 * quad], wo0b = W_out[33 + 2 * quad];
        const float wo1a = W_out[72 + 2 * quad], wo1b = W_out[73 + 2 * quad];
        ie0 = fmaf(wo0b, ih1, wo0a * ih0);
        ie1 = fmaf(wo1b, ih1, wo1a * ih0);
        ie0 += __shfl_xor(ie0, 16); ie1 += __shfl_xor(ie1, 16);
        ie0 += __shfl_xor(ie0, 32); ie1 += __shfl_xor(ie1, 32);
    }

    // his projection: lane has units {2n,2n+1} of 4 chains; reduce over n
    const float wo0a = W_out[2 * n],      wo0b = W_out[2 * n + 1];
    const float wo1a = W_out[40 + 2 * n], wo1b = W_out[40 + 2 * n + 1];
    float e0[4], e1[4];
#pragma unroll
    for (int r = 0; r < 4; ++r) {
        e0[r] = fmaf(wo0b, h1[r], wo0a * h0[r]);
        e1[r] = fmaf(wo1b, h1[r], wo1a * h0[r]);
#pragma unroll
        for (int m = 1; m <= 8; m <<= 1) {
            e0[r] += __shfl_xor(e0[r], m);
            e1[r] += __shfl_xor(e1[r], m);
        }
    }

    // gather int contribution for this quad's 4 chains (chain quad*4+r
    // lives at lane quad*4+r after the int reduction)
    float g0[4], g1[4];
#pragma unroll
    for (int r = 0; r < 4; ++r) {
        g0[r] = __shfl(ie0, quad * 4 + r);
        g1[r] = __shfl(ie1, quad * 4 + r);
    }

    if (n == 0) {
        const float bo0 = b_out[0], bo1 = b_out[1];
#pragma unroll
        for (int r = 0; r < 4; ++r) {
            const int chain = t * 128 + bbase + r;
            float2 o;
            o.x = e0[r] + g0[r] + bo0;
            o.y = e1[r] + g1[r] + bo1;
            reinterpret_cast<float2*>(out)[chain] = o;
        }
    }
}

extern "C" void kernel_launch(void* const* d_in, const int* in_sizes, int n_in,
                              void* d_out, int out_size, void* d_ws, size_t ws_size,
                              hipStream_t stream) {
    const float* inp     = (const float*)d_in[0];
    const float* Wih_his = (const float*)d_in[1];
    const float* Whh_his = (const float*)d_in[2];
    const float* bih_his = (const float*)d_in[3];
    const float* bhh_his = (const float*)d_in[4];
    const float* Wih_int = (const float*)d_in[5];
    const float* Whh_int = (const float*)d_in[6];
    const float* bih_int = (const float*)d_in[7];
    const float* bhh_int = (const float*)d_in[8];
    const float* W_out   = (const float*)d_in[9];
    const float* b_out   = (const float*)d_in[10];
    float* out  = (float*)d_out;
    float* ws   = (float*)d_ws;

    // pre-pass: prescale + permute weights (his fp16 Whh + int hi/lo Whh)
    prep_kernel<<<dim3(38), dim3(256), 0, stream>>>(
        Wih_his, Whh_his, bih_his, bhh_his,
        Wih_int, Whh_int, bih_int, bhh_int, ws);

    // fused his+int LSTM: 2048 waves, 16 chains each, 10 MFMAs per step
    fused_kernel<<<dim3(2048), dim3(64), 0, stream>>>(
        inp, ws, W_out, b_out, out);
}

// Round 5
// 185.850 us; speedup vs baseline: 1.2820x; 1.2820x over previous
//
#include <hip/hip_runtime.h>

// Trajectron sliding-window LSTM embed:
//   inputs [T=256, B=128, N=4, D=2] f32
//   his LSTM H=32 over n=3; int LSTM H=8 over n=0; window 64 ending at t
//   out[t,b,:] = [h_his | h_int] @ W_out.T + b_out   -> [256,128,2] f32
//
// Round-17 (zero-transpose recurrence): every fusion (R13 block, R16 wave)
// gave ZERO overlap and every int variant (LDS / shfl / hi-lo shfl) cost
// ~90us -> the per-step cross-lane h-exchange (LDS fences, ds_bpermute
// lgkm chains) is the latency killer; at 2 waves/SIMD (grid-capped:
// 2048 blocks / 256 CUs) nothing fills it, and wave_barrier fences also
// block compiler scheduling. This round makes the exchange VANISH:
//   his: D[gates][chains] = WhhP(A) . h(B) + xpart; gate-row perm
//     p=T*16+q*4+r -> (gate T>>1, unit q*8+4*(T&1)+r) makes lane(q,n)
//     compute h-units q*8..+7 of chain n == exactly its own B-frag slots
//     k=q*8+j for the next step. No LDS, no fence, no shfl. The x-part
//     is 8 extra MFMAs over the idle K-range (hi/lo exact split).
//   int: K-slot trick per quad: B[q*8+j] = {hh[2q],hh[2q+1],hh,hh,
//     hl[2q],hl[2q+1], x/bias}, A rows carry {w_hi,w_lo,w_hi,Wih,b}
//     -> Whh.h + Wih.x + b exact to ~1e-7, zero cross-lane, C=0.
// Both loops are pure-register and fence-free; compiler can finally
// schedule across the whole step. Numerics: his product identical to the
// verified fp16 path (absmax 4.88e-4); x-part/bias now MORE exact.

typedef float v4f __attribute__((ext_vector_type(4)));
typedef _Float16 h8v __attribute__((ext_vector_type(8)));

static __device__ __forceinline__ float fexp2(float x) {
    return __builtin_amdgcn_exp2f(x);
}
static __device__ __forceinline__ float frcp(float x) {
    return __builtin_amdgcn_rcpf(x);
}
static __device__ __forceinline__ unsigned short f2h(float f) {
    _Float16 h = (_Float16)f;
    unsigned short u;
    __builtin_memcpy(&u, &h, 2);
    return u;
}
static __device__ __forceinline__ float h2f(unsigned short u) {
    _Float16 h;
    __builtin_memcpy(&h, &u, 2);
    return (float)h;
}

#define LOG2E    1.442695041f
#define TWOLOG2E 2.885390082f
#define H16ONE   0x3C00u

// ws layout:
//   ushort [0,4096)     hisAW : A-frags WhhP his, [T=8][n=16][k=32]
//   ushort [4096,8192)  hisAX : A-frags x-part his (k<8 used), [8][16][32]
//   ushort [8192,9216)  intAW : A-frags int (Whh+Wih+b in K-slots), [2][16][32]
//   float  [8192,73728) eInt  : per-chain int contribution float2[32768]
//
// his perm: row p = T*16 + m (m = A-row = D-row): gate g = T>>1,
//   unit u = (m>>2)*8 + 4*(T&1) + (m&3), orig = g*32+u
// int perm: row p = T*16 + m: gate g = 2T + ((m&3)>>1),
//   unit u = 2*(m>>2) + (m&1), orig = g*8+u
// scale s = -log2e (i,f,o gates) / -2log2e (g gate)
__global__ __launch_bounds__(256) void prep_kernel(
    const float* __restrict__ Wih_his, const float* __restrict__ Whh_his,
    const float* __restrict__ bih_his, const float* __restrict__ bhh_his,
    const float* __restrict__ Wih_int, const float* __restrict__ Whh_int,
    const float* __restrict__ bih_int, const float* __restrict__ bhh_int,
    float* __restrict__ ws)
{
    const int i = blockIdx.x * 256 + threadIdx.x;
    unsigned short* wsu = reinterpret_cast<unsigned short*>(ws);

    if (i < 4096) {                     // hisAW: Whh part
        const int T = i >> 9, m = (i >> 5) & 15, k = i & 31;
        const int g = T >> 1;
        const int u = ((m >> 2) << 3) + ((T & 1) << 2) + (m & 3);
        const int orig = g * 32 + u;
        const float s = (g == 2) ? -TWOLOG2E : -LOG2E;
        wsu[i] = f2h(Whh_his[orig * 32 + k] * s);
    } else if (i < 8192) {              // hisAX: x-part (hi/lo exact)
        const int e = i - 4096;
        const int T = e >> 9, m = (e >> 5) & 15, k = e & 31;
        const int g = T >> 1;
        const int u = ((m >> 2) << 3) + ((T & 1) << 2) + (m & 3);
        const int orig = g * 32 + u;
        const float s = (g == 2) ? -TWOLOG2E : -LOG2E;
        const float w0 = Wih_his[orig * 2] * s;
        const float w1 = Wih_his[orig * 2 + 1] * s;
        const float b  = (bih_his[orig] + bhh_his[orig]) * s;
        unsigned short v = 0;
        switch (k) {
            case 0: v = f2h(w0); break;
            case 1: v = f2h(w1); break;
            case 2: v = f2h(b);  break;
            case 3: v = f2h(w0 - h2f(f2h(w0))); break;
            case 4: v = f2h(w1 - h2f(f2h(w1))); break;
            case 5: v = f2h(b  - h2f(f2h(b)));  break;
            case 6: v = f2h(w0); break;
            case 7: v = f2h(w1); break;
            default: v = 0; break;
        }
        wsu[4096 + e] = v;
    } else if (i < 9216) {              // intAW: Whh + Wih + b in K-slots
        const int e = i - 8192;
        const int T = e >> 9, m = (e >> 5) & 15, k = e & 31;
        const int q = k >> 3, j = k & 7;
        const int g = 2 * T + ((m & 3) >> 1);
        const int u = 2 * (m >> 2) + (m & 1);
        const int orig = g * 8 + u;
        const float s = (g == 2) ? -TWOLOG2E : -LOG2E;
        unsigned short v = 0;
        if (j < 6) {
            const int col = 2 * q + (j & 1);
            const float w = Whh_int[orig * 8 + col] * s;
            v = (j == 2 || j == 3) ? f2h(w - h2f(f2h(w))) : f2h(w);
        } else {
            const int comp = j & 1;
            if (q <= 1) {                       // w_hi . xh / w_hi . xl
                v = f2h(Wih_int[orig * 2 + comp] * s);
            } else if (q == 2) {                // w_lo . xh
                const float w = Wih_int[orig * 2 + comp] * s;
                v = f2h(w - h2f(f2h(w)));
            } else {                            // bias hi / lo
                const float b = (bih_int[orig] + bhh_int[orig]) * s;
                v = (comp == 0) ? f2h(b) : f2h(b - h2f(f2h(b)));
            }
        }
        wsu[8192 + e] = v;
    }
}

// ---------- int LSTM: 16 chains/wave, 2 MFMAs/step, zero cross-lane ------
__global__ __launch_bounds__(64) void intw_kernel(
    const float* __restrict__ inp, const float* __restrict__ ws,
    const float* __restrict__ W_out, float* __restrict__ eInt)
{
    const int lane = threadIdx.x;
    const int n    = lane & 15;
    const int q    = lane >> 4;
    const int Wd   = blockIdx.x;               // 0..2047
    const int t    = Wd >> 3;                  // uniform per wave
    const int bg   = Wd & 7;
    const int nsteps = (t >= 63) ? 64 : (t + 1);
    const int tau0   = (t >= 63) ? (t - 63) : 0;

    const unsigned short* wsu = reinterpret_cast<const unsigned short*>(ws);
    const h8v* wa = reinterpret_cast<const h8v*>(wsu + 8192);
    h8v AI[2];
#pragma unroll
    for (int T = 0; T < 2; ++T) AI[T] = wa[T * 64 + n * 4 + q];

    const int chain = bg * 16 + n;
    const float* xp = inp + tau0 * 1024 + chain * 8;
    float2 xv = *reinterpret_cast<const float2*>(xp);
    xp += 1024;

    union BU { unsigned u[4]; h8v h; } bh;
    bh.u[0] = bh.u[1] = bh.u[2] = bh.u[3] = 0;   // h = 0

    float cI0 = 0.f, cI1 = 0.f, ih0 = 0.f, ih1 = 0.f;

#pragma unroll 1
    for (int s = 0; s < nsteps; ++s) {
        float2 xn = make_float2(0.f, 0.f);
        if (s + 1 < nsteps)                     // wave-uniform branch
            xn = *reinterpret_cast<const float2*>(xp);
        xp += 1024;

        // B-frag slot d3: q0/q2 -> (xh,yh); q1 -> (xl,yl); q3 -> (1,1)
        {
            const unsigned short xh = f2h(xv.x), yh = f2h(xv.y);
            const unsigned short xl = f2h(xv.x - h2f(xh));
            const unsigned short yl = f2h(xv.y - h2f(yh));
            const unsigned pkh = ((unsigned)yh << 16) | xh;
            const unsigned pkl = ((unsigned)yl << 16) | xl;
            bh.u[3] = (q == 3) ? ((H16ONE << 16) | H16ONE)
                               : ((q == 1) ? pkl : pkh);
        }

        const v4f z = {0.f, 0.f, 0.f, 0.f};
        const v4f D0 = __builtin_amdgcn_mfma_f32_16x16x32_f16(AI[0], bh.h, z, 0, 0, 0);
        const v4f D1 = __builtin_amdgcn_mfma_f32_16x16x32_f16(AI[1], bh.h, z, 0, 0, 0);

        // lane-local activations: units {2q, 2q+1} of chain n
        {
            const float si = frcp(1.f + fexp2(D0[0]));
            const float sf = frcp(1.f + fexp2(D0[2]));
            const float tg = fmaf(2.f, frcp(1.f + fexp2(D1[0])), -1.f);
            const float so = frcp(1.f + fexp2(D1[2]));
            const float cn = fmaf(sf, cI0, si * tg);
            cI0 = cn;
            ih0 = so * fmaf(-2.f, frcp(1.f + fexp2(TWOLOG2E * cn)), 1.f);
        }
        {
            const float si = frcp(1.f + fexp2(D0[1]));
            const float sf = frcp(1.f + fexp2(D0[3]));
            const float tg = fmaf(2.f, frcp(1.f + fexp2(D1[1])), -1.f);
            const float so = frcp(1.f + fexp2(D1[3]));
            const float cn = fmaf(sf, cI1, si * tg);
            cI1 = cn;
            ih1 = so * fmaf(-2.f, frcp(1.f + fexp2(TWOLOG2E * cn)), 1.f);
        }

        // h -> B-frag, fully in-lane: hh pair (j0,j1 = j2,j3), hl pair
        {
            const unsigned short hh0 = f2h(ih0), hh1 = f2h(ih1);
            const unsigned short hl0 = f2h(ih0 - h2f(hh0));
            const unsigned short hl1 = f2h(ih1 - h2f(hh1));
            bh.u[0] = ((unsigned)hh1 << 16) | hh0;
            bh.u[1] = bh.u[0];
            bh.u[2] = ((unsigned)hl1 << 16) | hl0;
        }

        xv = xn;
    }

    // projection: lane(q,n) has units {2q,2q+1} of chain n; reduce over q
    const float wo0a = W_out[32 + 2 * q], wo0b = W_out[33 + 2 * q];
    const float wo1a = W_out[72 + 2 * q], wo1b = W_out[73 + 2 * q];
    float e0 = fmaf(wo0b, ih1, wo0a * ih0);
    float e1 = fmaf(wo1b, ih1, wo1a * ih0);
    e0 += __shfl_xor(e0, 16); e1 += __shfl_xor(e1, 16);
    e0 += __shfl_xor(e0, 32); e1 += __shfl_xor(e1, 32);
    if (lane < 16) {
        float2 o; o.x = e0; o.y = e1;
        reinterpret_cast<float2*>(eInt)[t * 128 + chain] = o;
    }
}

// ---------- his LSTM: 16 chains/wave, 16 MFMAs/step, zero transpose ------
__global__ __launch_bounds__(64) void hisw_kernel(
    const float* __restrict__ inp, const float* __restrict__ ws,
    const float* __restrict__ W_out, const float* __restrict__ b_out,
    const float* __restrict__ eInt, float* __restrict__ out)
{
    const int lane = threadIdx.x;
    const int n    = lane & 15;
    const int q    = lane >> 4;
    const int Wd   = blockIdx.x;               // 0..2047
    const int t    = Wd >> 3;                  // uniform per wave
    const int bg   = Wd & 7;
    const int nsteps = (t >= 63) ? 64 : (t + 1);
    const int tau0   = (t >= 63) ? (t - 63) : 0;

    const unsigned short* wsu = reinterpret_cast<const unsigned short*>(ws);
    const h8v* wa = reinterpret_cast<const h8v*>(wsu);          // hisAW
    const h8v* wx = reinterpret_cast<const h8v*>(wsu + 4096);   // hisAX
    h8v AW[8], AX[8];
#pragma unroll
    for (int T = 0; T < 8; ++T) {
        AW[T] = wa[T * 64 + n * 4 + q];
        AX[T] = wx[T * 64 + n * 4 + q];
    }

    const int chain = bg * 16 + n;
    const float* xp = inp + tau0 * 1024 + chain * 8 + 6;  // n=3 slot
    float2 xv = *reinterpret_cast<const float2*>(xp);
    xp += 1024;

    union BU { unsigned u[4]; h8v h; } bh;   // h state (B-frag)
    bh.u[0] = bh.u[1] = bh.u[2] = bh.u[3] = 0;
    float c[8] = {0.f, 0.f, 0.f, 0.f, 0.f, 0.f, 0.f, 0.f};
    float h[8] = {0.f, 0.f, 0.f, 0.f, 0.f, 0.f, 0.f, 0.f};

#pragma unroll 1
    for (int s = 0; s < nsteps; ++s) {
        float2 xn = make_float2(0.f, 0.f);
        if (s + 1 < nsteps)                 // wave-uniform branch
            xn = *reinterpret_cast<const float2*>(xp);
        xp += 1024;

        // Bx: q0 lanes carry [xh, yh, 1, xh, yh, 1, xl, yl]; others 0
        union BU bx;
        {
            const unsigned short xh = f2h(xv.x), yh = f2h(xv.y);
            const unsigned short xl = f2h(xv.x - h2f(xh));
            const unsigned short yl = f2h(xv.y - h2f(yh));
            bx.u[0] = ((unsigned)yh << 16) | xh;      // j1,j0
            bx.u[1] = ((unsigned)xh << 16) | H16ONE;  // j3,j2
            bx.u[2] = (H16ONE << 16) | yh;            // j5,j4
            bx.u[3] = ((unsigned)yl << 16) | xl;      // j7,j6
            if (q != 0) { bx.u[0] = 0; bx.u[1] = 0; bx.u[2] = 0; bx.u[3] = 0; }
        }

        // 16 MFMAs: D[T] = WhhP_T . h + (WihP_T . [x;1] via idle K)
        const v4f z = {0.f, 0.f, 0.f, 0.f};
        v4f D[8];
#pragma unroll
        for (int T = 0; T < 8; ++T) {
            const v4f cx = __builtin_amdgcn_mfma_f32_16x16x32_f16(AX[T], bx.h, z, 0, 0, 0);
            D[T] = __builtin_amdgcn_mfma_f32_16x16x32_f16(AW[T], bh.h, cx, 0, 0, 0);
        }

        // lane-local activations: 8 units (q*8+ww) of chain n
        // gate g of local unit ww: D[2g + (ww>>2)][ww&3]
#pragma unroll
        for (int hi = 0; hi < 2; ++hi) {
#pragma unroll
            for (int lo = 0; lo < 4; ++lo) {
                const int ww = hi * 4 + lo;
                const float si = frcp(1.f + fexp2(D[hi][lo]));
                const float sf = frcp(1.f + fexp2(D[2 + hi][lo]));
                const float tg = fmaf(2.f, frcp(1.f + fexp2(D[4 + hi][lo])), -1.f);
                const float so = frcp(1.f + fexp2(D[6 + hi][lo]));
                const float cn = fmaf(sf, c[ww], si * tg);
                c[ww] = cn;
                h[ww] = so * fmaf(-2.f, frcp(1.f + fexp2(TWOLOG2E * cn)), 1.f);
            }
        }

        // h -> B-frag, fully in-lane (lane's units are its own B slots)
#pragma unroll
        for (int d = 0; d < 4; ++d)
            bh.u[d] = ((unsigned)f2h(h[2 * d + 1]) << 16) | f2h(h[2 * d]);

        xv = xn;
    }

    // projection: lane(q,n) has units q*8..q*8+7 of chain n; reduce over q
    const v4f w0a = *reinterpret_cast<const v4f*>(W_out + q * 8);
    const v4f w0b = *reinterpret_cast<const v4f*>(W_out + q * 8 + 4);
    const v4f w1a = *reinterpret_cast<const v4f*>(W_out + 40 + q * 8);
    const v4f w1b = *reinterpret_cast<const v4f*>(W_out + 40 + q * 8 + 4);
    float e0 = 0.f, e1 = 0.f;
#pragma unroll
    for (int j = 0; j < 4; ++j) {
        e0 = fmaf(w0a[j], h[j], fmaf(w0b[j], h[4 + j], e0));
        e1 = fmaf(w1a[j], h[j], fmaf(w1b[j], h[4 + j], e1));
    }
    e0 += __shfl_xor(e0, 16); e1 += __shfl_xor(e1, 16);
    e0 += __shfl_xor(e0, 32); e1 += __shfl_xor(e1, 32);

    if (lane < 16) {
        const float2 ei = reinterpret_cast<const float2*>(eInt)[t * 128 + chain];
        float2 o;
        o.x = e0 + ei.x + b_out[0];
        o.y = e1 + ei.y + b_out[1];
        reinterpret_cast<float2*>(out)[t * 128 + chain] = o;
    }
}

extern "C" void kernel_launch(void* const* d_in, const int* in_sizes, int n_in,
                              void* d_out, int out_size, void* d_ws, size_t ws_size,
                              hipStream_t stream) {
    const float* inp     = (const float*)d_in[0];
    const float* Wih_his = (const float*)d_in[1];
    const float* Whh_his = (const float*)d_in[2];
    const float* bih_his = (const float*)d_in[3];
    const float* bhh_his = (const float*)d_in[4];
    const float* Wih_int = (const float*)d_in[5];
    const float* Whh_int = (const float*)d_in[6];
    const float* bih_int = (const float*)d_in[7];
    const float* bhh_int = (const float*)d_in[8];
    const float* W_out   = (const float*)d_in[9];
    const float* b_out   = (const float*)d_in[10];
    float* out  = (float*)d_out;
    float* ws   = (float*)d_ws;
    float* eInt = ws + 8192;

    // pre-pass: build permuted fp16 A-frag tables (hi/lo exact splits)
    prep_kernel<<<dim3(36), dim3(256), 0, stream>>>(
        Wih_his, Whh_his, bih_his, bhh_his,
        Wih_int, Whh_int, bih_int, bhh_int, ws);

    // int LSTM: 2048 waves, 16 chains each, fence-free pure-register loop
    intw_kernel<<<dim3(2048), dim3(64), 0, stream>>>(inp, ws, W_out, eInt);

    // his LSTM: 2048 waves, 16 chains each, fence-free pure-register loop
    hisw_kernel<<<dim3(2048), dim3(64), 0, stream>>>(
        inp, ws, W_out, b_out, eInt, out);
}

// Round 10
// 182.558 us; speedup vs baseline: 1.3052x; 1.0180x over previous
//
#include <hip/hip_runtime.h>

// Trajectron sliding-window LSTM embed:
//   inputs [T=256, B=128, N=4, D=2] f32
//   his LSTM H=32 over n=3; int LSTM H=8 over n=0; window 64 ending at t
//   out[t,b,:] = [h_his | h_int] @ W_out.T + b_out   -> [256,128,2] f32
//
// Round-22: R19/20/21 never ran (three container failures). This is the
// same fence-free in-wave fusion, with the never-yet-compiled cvt_pkrtz
// wrapper replaced by the R17-PROVEN f2h(rte) packing (compiles, passed
// at absmax 4.88e-4). hi/lo splits stay exact under rte: lo = x-h2f(hi)
// absorbs hi's rounding. Structure:
//   his: D[T] = WhhP_T . h_his + (WihP_T . [x;1] via idle K); lane(q,n)
//     computes h-units q*8..+7 of chain n == its own next-step B-frag
//     slots -> recurrence is pure-register, no LDS/fence/shfl.
//   int: D[T] = intAW_T . B, B K-slots carry {h_hi, h_hi, h_lo, x/1};
//     zero cross-lane. 18 MFMAs/step total, one dispatch, one epilogue
//     q-reduction. int's independent work fills his's dependency bubbles
//     (hisw alone: 90.3us @ VALUBusy 65%; intw alone ~42us).

typedef float v4f __attribute__((ext_vector_type(4)));
typedef _Float16 h8v __attribute__((ext_vector_type(8)));

static __device__ __forceinline__ float fexp2(float x) {
    return __builtin_amdgcn_exp2f(x);
}
static __device__ __forceinline__ float frcp(float x) {
    return __builtin_amdgcn_rcpf(x);
}
static __device__ __forceinline__ unsigned short f2h(float f) {
    _Float16 h = (_Float16)f;
    unsigned short u;
    __builtin_memcpy(&u, &h, 2);
    return u;
}
static __device__ __forceinline__ float h2f(unsigned short u) {
    _Float16 h;
    __builtin_memcpy(&h, &u, 2);
    return (float)h;
}

#define LOG2E    1.442695041f
#define TWOLOG2E 2.885390082f
#define H16ONE   0x3C00u

// ws layout:
//   ushort [0,4096)     hisAW : A-frags WhhP his, [T=8][n=16][k=32]
//   ushort [4096,8192)  hisAX : A-frags x-part his (k<8 used), [8][16][32]
//   ushort [8192,9216)  intAW : A-frags int (Whh+Wih+b in K-slots), [2][16][32]
//
// his perm: row p = T*16 + m (m = A-row = D-row): gate g = T>>1,
//   unit u = (m>>2)*8 + 4*(T&1) + (m&3), orig = g*32+u
// int perm: row p = T*16 + m: gate g = 2T + ((m&3)>>1),
//   unit u = 2*(m>>2) + (m&1), orig = g*8+u
// scale s = -log2e (i,f,o gates) / -2log2e (g gate)
__global__ __launch_bounds__(256) void prep_kernel(
    const float* __restrict__ Wih_his, const float* __restrict__ Whh_his,
    const float* __restrict__ bih_his, const float* __restrict__ bhh_his,
    const float* __restrict__ Wih_int, const float* __restrict__ Whh_int,
    const float* __restrict__ bih_int, const float* __restrict__ bhh_int,
    float* __restrict__ ws)
{
    const int i = blockIdx.x * 256 + threadIdx.x;
    unsigned short* wsu = reinterpret_cast<unsigned short*>(ws);

    if (i < 4096) {                     // hisAW: Whh part
        const int T = i >> 9, m = (i >> 5) & 15, k = i & 31;
        const int g = T >> 1;
        const int u = ((m >> 2) << 3) + ((T & 1) << 2) + (m & 3);
        const int orig = g * 32 + u;
        const float s = (g == 2) ? -TWOLOG2E : -LOG2E;
        wsu[i] = f2h(Whh_his[orig * 32 + k] * s);
    } else if (i < 8192) {              // hisAX: x-part (hi/lo exact)
        const int e = i - 4096;
        const int T = e >> 9, m = (e >> 5) & 15, k = e & 31;
        const int g = T >> 1;
        const int u = ((m >> 2) << 3) + ((T & 1) << 2) + (m & 3);
        const int orig = g * 32 + u;
        const float s = (g == 2) ? -TWOLOG2E : -LOG2E;
        const float w0 = Wih_his[orig * 2] * s;
        const float w1 = Wih_his[orig * 2 + 1] * s;
        const float b  = (bih_his[orig] + bhh_his[orig]) * s;
        unsigned short v = 0;
        switch (k) {
            case 0: v = f2h(w0); break;
            case 1: v = f2h(w1); break;
            case 2: v = f2h(b);  break;
            case 3: v = f2h(w0 - h2f(f2h(w0))); break;
            case 4: v = f2h(w1 - h2f(f2h(w1))); break;
            case 5: v = f2h(b  - h2f(f2h(b)));  break;
            case 6: v = f2h(w0); break;
            case 7: v = f2h(w1); break;
            default: v = 0; break;
        }
        wsu[4096 + e] = v;
    } else if (i < 9216) {              // intAW: Whh + Wih + b in K-slots
        const int e = i - 8192;
        const int T = e >> 9, m = (e >> 5) & 15, k = e & 31;
        const int q = k >> 3, j = k & 7;
        const int g = 2 * T + ((m & 3) >> 1);
        const int u = 2 * (m >> 2) + (m & 1);
        const int orig = g * 8 + u;
        const float s = (g == 2) ? -TWOLOG2E : -LOG2E;
        unsigned short v = 0;
        if (j < 6) {
            const int col = 2 * q + (j & 1);
            const float w = Whh_int[orig * 8 + col] * s;
            v = (j == 2 || j == 3) ? f2h(w - h2f(f2h(w))) : f2h(w);
        } else {
            const int comp = j & 1;
            if (q <= 1) {                       // w_hi . xh / w_hi . xl
                v = f2h(Wih_int[orig * 2 + comp] * s);
            } else if (q == 2) {                // w_lo . xh
                const float w = Wih_int[orig * 2 + comp] * s;
                v = f2h(w - h2f(f2h(w)));
            } else {                            // bias hi / lo
                const float b = (bih_int[orig] + bhh_int[orig]) * s;
                v = (comp == 0) ? f2h(b) : f2h(b - h2f(f2h(b)));
            }
        }
        wsu[8192 + e] = v;
    }
}

// ---------- fused his+int LSTM: 16 chains/wave, 18 MFMAs/step, no LDS ----
__global__ __launch_bounds__(64) void fusedw_kernel(
    const float* __restrict__ inp, const float* __restrict__ ws,
    const float* __restrict__ W_out, const float* __restrict__ b_out,
    float* __restrict__ out)
{
    const int lane = threadIdx.x;
    const int n    = lane & 15;
    const int q    = lane >> 4;
    const int Wd   = blockIdx.x;               // 0..2047
    const int t    = Wd >> 3;                  // uniform per wave
    const int bg   = Wd & 7;
    const int nsteps = (t >= 63) ? 64 : (t + 1);
    const int tau0   = (t >= 63) ? (t - 63) : 0;

    const unsigned short* wsu = reinterpret_cast<const unsigned short*>(ws);
    const h8v* wa = reinterpret_cast<const h8v*>(wsu);          // hisAW
    const h8v* wx = reinterpret_cast<const h8v*>(wsu + 4096);   // hisAX
    const h8v* wi = reinterpret_cast<const h8v*>(wsu + 8192);   // intAW
    h8v AW[8], AX[8], AI[2];
#pragma unroll
    for (int T = 0; T < 8; ++T) {
        AW[T] = wa[T * 64 + n * 4 + q];
        AX[T] = wx[T * 64 + n * 4 + q];
    }
#pragma unroll
    for (int T = 0; T < 2; ++T) AI[T] = wi[T * 64 + n * 4 + q];

    const int chain = bg * 16 + n;
    const float* xb = inp + tau0 * 1024 + chain * 8;
    float2 xvH = *reinterpret_cast<const float2*>(xb + 6);   // his: n=3 slot
    float2 xvI = *reinterpret_cast<const float2*>(xb);       // int: n=0 slot
    xb += 1024;

    union BU { unsigned u[4]; h8v h; };
    BU bhH; bhH.u[0] = bhH.u[1] = bhH.u[2] = bhH.u[3] = 0;   // his h
    BU bhI; bhI.u[0] = bhI.u[1] = bhI.u[2] = bhI.u[3] = 0;   // int h
    float cH[8] = {0.f, 0.f, 0.f, 0.f, 0.f, 0.f, 0.f, 0.f};
    float hH[8] = {0.f, 0.f, 0.f, 0.f, 0.f, 0.f, 0.f, 0.f};
    float cI0 = 0.f, cI1 = 0.f, ih0 = 0.f, ih1 = 0.f;

#pragma unroll 1
    for (int s = 0; s < nsteps; ++s) {
        float2 xnH = make_float2(0.f, 0.f);
        float2 xnI = make_float2(0.f, 0.f);
        if (s + 1 < nsteps) {               // wave-uniform branch
            xnH = *reinterpret_cast<const float2*>(xb + 6);
            xnI = *reinterpret_cast<const float2*>(xb);
        }
        xb += 1024;

        // his Bx: q0 lanes carry [xh, yh, 1, xh, yh, 1, xl, yl]; others 0
        BU bx;
        {
            const unsigned short xh = f2h(xvH.x), yh = f2h(xvH.y);
            const unsigned short xl = f2h(xvH.x - h2f(xh));
            const unsigned short yl = f2h(xvH.y - h2f(yh));
            bx.u[0] = ((unsigned)yh << 16) | xh;             // j1,j0
            bx.u[1] = ((unsigned)xh << 16) | H16ONE;         // j3=xh, j2=1
            bx.u[2] = (H16ONE << 16) | yh;                   // j5=1, j4=yh
            bx.u[3] = ((unsigned)yl << 16) | xl;             // j7,j6
            if (q != 0) { bx.u[0] = 0; bx.u[1] = 0; bx.u[2] = 0; bx.u[3] = 0; }
        }
        // int B x-slot: q0/q2 -> (xh,yh); q1 -> (xl,yl); q3 -> (1,1)
        {
            const unsigned short xh = f2h(xvI.x), yh = f2h(xvI.y);
            const unsigned short xl = f2h(xvI.x - h2f(xh));
            const unsigned short yl = f2h(xvI.y - h2f(yh));
            const unsigned ph = ((unsigned)yh << 16) | xh;
            const unsigned pl = ((unsigned)yl << 16) | xl;
            bhI.u[3] = (q == 3) ? ((H16ONE << 16) | H16ONE)
                                : ((q == 1) ? pl : ph);
        }

        const v4f z = {0.f, 0.f, 0.f, 0.f};

        // int: 2 MFMAs (fully independent of his chain)
        const v4f E0 = __builtin_amdgcn_mfma_f32_16x16x32_f16(AI[0], bhI.h, z, 0, 0, 0);
        const v4f E1 = __builtin_amdgcn_mfma_f32_16x16x32_f16(AI[1], bhI.h, z, 0, 0, 0);

        // his: 16 MFMAs D[T] = WhhP_T . h + WihP_T . [x;1]
        v4f D[8];
#pragma unroll
        for (int T = 0; T < 8; ++T) {
            const v4f cx = __builtin_amdgcn_mfma_f32_16x16x32_f16(AX[T], bx.h, z, 0, 0, 0);
            D[T] = __builtin_amdgcn_mfma_f32_16x16x32_f16(AW[T], bhH.h, cx, 0, 0, 0);
        }

        // int activations: units {2q, 2q+1} of chain n
        {
            const float si = frcp(1.f + fexp2(E0[0]));
            const float sf = frcp(1.f + fexp2(E0[2]));
            const float tg = fmaf(2.f, frcp(1.f + fexp2(E1[0])), -1.f);
            const float so = frcp(1.f + fexp2(E1[2]));
            const float cn = fmaf(sf, cI0, si * tg);
            cI0 = cn;
            ih0 = so * fmaf(-2.f, frcp(1.f + fexp2(TWOLOG2E * cn)), 1.f);
        }
        {
            const float si = frcp(1.f + fexp2(E0[1]));
            const float sf = frcp(1.f + fexp2(E0[3]));
            const float tg = fmaf(2.f, frcp(1.f + fexp2(E1[1])), -1.f);
            const float so = frcp(1.f + fexp2(E1[3]));
            const float cn = fmaf(sf, cI1, si * tg);
            cI1 = cn;
            ih1 = so * fmaf(-2.f, frcp(1.f + fexp2(TWOLOG2E * cn)), 1.f);
        }
        // int h -> B-frag, in-lane (hi/lo corrected, rte-exact)
        {
            const unsigned short hh0 = f2h(ih0), hh1 = f2h(ih1);
            const unsigned short hl0 = f2h(ih0 - h2f(hh0));
            const unsigned short hl1 = f2h(ih1 - h2f(hh1));
            bhI.u[0] = ((unsigned)hh1 << 16) | hh0;
            bhI.u[1] = bhI.u[0];
            bhI.u[2] = ((unsigned)hl1 << 16) | hl0;
        }

        // his activations: 8 units (q*8+ww) of chain n
#pragma unroll
        for (int hi = 0; hi < 2; ++hi) {
#pragma unroll
            for (int lo = 0; lo < 4; ++lo) {
                const int ww = hi * 4 + lo;
                const float si = frcp(1.f + fexp2(D[hi][lo]));
                const float sf = frcp(1.f + fexp2(D[2 + hi][lo]));
                const float tg = fmaf(2.f, frcp(1.f + fexp2(D[4 + hi][lo])), -1.f);
                const float so = frcp(1.f + fexp2(D[6 + hi][lo]));
                const float cn = fmaf(sf, cH[ww], si * tg);
                cH[ww] = cn;
                hH[ww] = so * fmaf(-2.f, frcp(1.f + fexp2(TWOLOG2E * cn)), 1.f);
            }
        }
        // his h -> B-frag, in-lane (uncorrected: keep verified rte f2h)
#pragma unroll
        for (int d = 0; d < 4; ++d)
            bhH.u[d] = ((unsigned)f2h(hH[2 * d + 1]) << 16) | f2h(hH[2 * d]);

        xvH = xnH;
        xvI = xnI;
    }

    // ---- epilogue: combined projection, one q-reduction -----------------
    // his partial: units q*8..+7; int partial: units {2q,2q+1}
    const v4f w0a = *reinterpret_cast<const v4f*>(W_out + q * 8);
    const v4f w0b = *reinterpret_cast<const v4f*>(W_out + q * 8 + 4);
    const v4f w1a = *reinterpret_cast<const v4f*>(W_out + 40 + q * 8);
    const v4f w1b = *reinterpret_cast<const v4f*>(W_out + 40 + q * 8 + 4);
    float e0 = fmaf(W_out[33 + 2 * q], ih1, W_out[32 + 2 * q] * ih0);
    float e1 = fmaf(W_out[73 + 2 * q], ih1, W_out[72 + 2 * q] * ih0);
#pragma unroll
    for (int j = 0; j < 4; ++j) {
        e0 = fmaf(w0a[j], hH[j], fmaf(w0b[j], hH[4 + j], e0));
        e1 = fmaf(w1a[j], hH[j], fmaf(w1b[j], hH[4 + j], e1));
    }
    e0 += __shfl_xor(e0, 16); e1 += __shfl_xor(e1, 16);
    e0 += __shfl_xor(e0, 32); e1 += __shfl_xor(e1, 32);

    if (lane < 16) {
        float2 o;
        o.x = e0 + b_out[0];
        o.y = e1 + b_out[1];
        reinterpret_cast<float2*>(out)[t * 128 + chain] = o;
    }
}

extern "C" void kernel_launch(void* const* d_in, const int* in_sizes, int n_in,
                              void* d_out, int out_size, void* d_ws, size_t ws_size,
                              hipStream_t stream) {
    const float* inp     = (const float*)d_in[0];
    const float* Wih_his = (const float*)d_in[1];
    const float* Whh_his = (const float*)d_in[2];
    const float* bih_his = (const float*)d_in[3];
    const float* bhh_his = (const float*)d_in[4];
    const float* Wih_int = (const float*)d_in[5];
    const float* Whh_int = (const float*)d_in[6];
    const float* bih_int = (const float*)d_in[7];
    const float* bhh_int = (const float*)d_in[8];
    const float* W_out   = (const float*)d_in[9];
    const float* b_out   = (const float*)d_in[10];
    float* out  = (float*)d_out;
    float* ws   = (float*)d_ws;

    // pre-pass: build permuted fp16 A-frag tables (hi/lo exact splits)
    prep_kernel<<<dim3(36), dim3(256), 0, stream>>>(
        Wih_his, Whh_his, bih_his, bhh_his,
        Wih_int, Whh_int, bih_int, bhh_int, ws);

    // fused his+int LSTM: 2048 waves, 16 chains each, fence-free loop
    fusedw_kernel<<<dim3(2048), dim3(64), 0, stream>>>(
        inp, ws, W_out, b_out, out);
}

// Round 11
// 178.992 us; speedup vs baseline: 1.3312x; 1.0199x over previous
//
#include <hip/hip_runtime.h>

// Trajectron sliding-window LSTM embed:
//   inputs [T=256, B=128, N=4, D=2] f32
//   his LSTM H=32 over n=3; int LSTM H=8 over n=0; window 64 ending at t
//   out[t,b,:] = [h_his | h_int] @ W_out.T + b_out   -> [256,128,2] f32
//
// Round-23 (trans-diet): R22's fused kernel measured 121us with VALUBusy
// 62% -- busy-time (75us) matches 100 trans-ops/step/lane x 16cy exactly:
// the kernel is TRANSCENDENTAL-pipe-bound (10 trans per LSTM unit x 10
// units/lane). This round cuts 10 -> 7 trans/unit via shared-denominator
// algebra (exact in real arithmetic):
//   cn = [ (1+ei)(1+eg)c + (1-eg)(1+ef) ] / [(1+ei)(1+eg)(1+ef)]  (1 rcp)
//   h  = (ec-1) / [(1+eo)(1+ec)]                                  (1 rcp)
// with e* clamped (1e12/1e18) so products never reach INF (no NaN path;
// clamp engages only where sigma==0 / tanh==1 anyway). -30% trans issue.
// Everything else byte-identical to the verified R22 kernel (absmax 4.88e-4).

typedef float v4f __attribute__((ext_vector_type(4)));
typedef _Float16 h8v __attribute__((ext_vector_type(8)));

static __device__ __forceinline__ float fexp2(float x) {
    return __builtin_amdgcn_exp2f(x);
}
static __device__ __forceinline__ float frcp(float x) {
    return __builtin_amdgcn_rcpf(x);
}
static __device__ __forceinline__ unsigned short f2h(float f) {
    _Float16 h = (_Float16)f;
    unsigned short u;
    __builtin_memcpy(&u, &h, 2);
    return u;
}
static __device__ __forceinline__ float h2f(unsigned short u) {
    _Float16 h;
    __builtin_memcpy(&h, &u, 2);
    return (float)h;
}

#define LOG2E    1.442695041f
#define TWOLOG2E 2.885390082f
#define H16ONE   0x3C00u

// 7-trans LSTM unit update (5 exp2 + 2 rcp; was 10 trans).
// Inputs are prescaled gate pre-activations: Di=-i*log2e, Df=-f*log2e,
// Dg=-2g*log2e, Do=-o*log2e (from the MFMA). c,h updated in place.
static __device__ __forceinline__ void lstm_unit(
    float Di, float Df, float Dg, float Do, float& c, float& h)
{
    const float ei = fminf(fexp2(Di), 1e12f);
    const float ef = fminf(fexp2(Df), 1e12f);
    const float eg = fminf(fexp2(Dg), 1e12f);
    const float eo = fminf(fexp2(Do), 1e18f);
    const float pi1 = 1.f + ei, pf1 = 1.f + ef, pg1 = 1.f + eg;
    const float p12 = pi1 * pg1;                  // (1+ei)(1+eg)
    const float r3  = frcp(p12 * pf1);            // <= 1e36, no INF
    const float cn  = fmaf(p12, c, (1.f - eg) * pf1) * r3;
    c = cn;
    const float ec = fminf(fexp2(TWOLOG2E * cn), 1e18f);
    h = (ec - 1.f) * frcp((1.f + eo) * (1.f + ec));
}

// ws layout:
//   ushort [0,4096)     hisAW : A-frags WhhP his, [T=8][n=16][k=32]
//   ushort [4096,8192)  hisAX : A-frags x-part his (k<8 used), [8][16][32]
//   ushort [8192,9216)  intAW : A-frags int (Whh+Wih+b in K-slots), [2][16][32]
//
// his perm: row p = T*16 + m (m = A-row = D-row): gate g = T>>1,
//   unit u = (m>>2)*8 + 4*(T&1) + (m&3), orig = g*32+u
// int perm: row p = T*16 + m: gate g = 2T + ((m&3)>>1),
//   unit u = 2*(m>>2) + (m&1), orig = g*8+u
// scale s = -log2e (i,f,o gates) / -2log2e (g gate)
__global__ __launch_bounds__(256) void prep_kernel(
    const float* __restrict__ Wih_his, const float* __restrict__ Whh_his,
    const float* __restrict__ bih_his, const float* __restrict__ bhh_his,
    const float* __restrict__ Wih_int, const float* __restrict__ Whh_int,
    const float* __restrict__ bih_int, const float* __restrict__ bhh_int,
    float* __restrict__ ws)
{
    const int i = blockIdx.x * 256 + threadIdx.x;
    unsigned short* wsu = reinterpret_cast<unsigned short*>(ws);

    if (i < 4096) {                     // hisAW: Whh part
        const int T = i >> 9, m = (i >> 5) & 15, k = i & 31;
        const int g = T >> 1;
        const int u = ((m >> 2) << 3) + ((T & 1) << 2) + (m & 3);
        const int orig = g * 32 + u;
        const float s = (g == 2) ? -TWOLOG2E : -LOG2E;
        wsu[i] = f2h(Whh_his[orig * 32 + k] * s);
    } else if (i < 8192) {              // hisAX: x-part (hi/lo exact)
        const int e = i - 4096;
        const int T = e >> 9, m = (e >> 5) & 15, k = e & 31;
        const int g = T >> 1;
        const int u = ((m >> 2) << 3) + ((T & 1) << 2) + (m & 3);
        const int orig = g * 32 + u;
        const float s = (g == 2) ? -TWOLOG2E : -LOG2E;
        const float w0 = Wih_his[orig * 2] * s;
        const float w1 = Wih_his[orig * 2 + 1] * s;
        const float b  = (bih_his[orig] + bhh_his[orig]) * s;
        unsigned short v = 0;
        switch (k) {
            case 0: v = f2h(w0); break;
            case 1: v = f2h(w1); break;
            case 2: v = f2h(b);  break;
            case 3: v = f2h(w0 - h2f(f2h(w0))); break;
            case 4: v = f2h(w1 - h2f(f2h(w1))); break;
            case 5: v = f2h(b  - h2f(f2h(b)));  break;
            case 6: v = f2h(w0); break;
            case 7: v = f2h(w1); break;
            default: v = 0; break;
        }
        wsu[4096 + e] = v;
    } else if (i < 9216) {              // intAW: Whh + Wih + b in K-slots
        const int e = i - 8192;
        const int T = e >> 9, m = (e >> 5) & 15, k = e & 31;
        const int q = k >> 3, j = k & 7;
        const int g = 2 * T + ((m & 3) >> 1);
        const int u = 2 * (m >> 2) + (m & 1);
        const int orig = g * 8 + u;
        const float s = (g == 2) ? -TWOLOG2E : -LOG2E;
        unsigned short v = 0;
        if (j < 6) {
            const int col = 2 * q + (j & 1);
            const float w = Whh_int[orig * 8 + col] * s;
            v = (j == 2 || j == 3) ? f2h(w - h2f(f2h(w))) : f2h(w);
        } else {
            const int comp = j & 1;
            if (q <= 1) {                       // w_hi . xh / w_hi . xl
                v = f2h(Wih_int[orig * 2 + comp] * s);
            } else if (q == 2) {                // w_lo . xh
                const float w = Wih_int[orig * 2 + comp] * s;
                v = f2h(w - h2f(f2h(w)));
            } else {                            // bias hi / lo
                const float b = (bih_int[orig] + bhh_int[orig]) * s;
                v = (comp == 0) ? f2h(b) : f2h(b - h2f(f2h(b)));
            }
        }
        wsu[8192 + e] = v;
    }
}

// ---------- fused his+int LSTM: 16 chains/wave, 18 MFMAs/step, no LDS ----
__global__ __launch_bounds__(64) void fusedw_kernel(
    const float* __restrict__ inp, const float* __restrict__ ws,
    const float* __restrict__ W_out, const float* __restrict__ b_out,
    float* __restrict__ out)
{
    const int lane = threadIdx.x;
    const int n    = lane & 15;
    const int q    = lane >> 4;
    const int Wd   = blockIdx.x;               // 0..2047
    const int t    = Wd >> 3;                  // uniform per wave
    const int bg   = Wd & 7;
    const int nsteps = (t >= 63) ? 64 : (t + 1);
    const int tau0   = (t >= 63) ? (t - 63) : 0;

    const unsigned short* wsu = reinterpret_cast<const unsigned short*>(ws);
    const h8v* wa = reinterpret_cast<const h8v*>(wsu);          // hisAW
    const h8v* wx = reinterpret_cast<const h8v*>(wsu + 4096);   // hisAX
    const h8v* wi = reinterpret_cast<const h8v*>(wsu + 8192);   // intAW
    h8v AW[8], AX[8], AI[2];
#pragma unroll
    for (int T = 0; T < 8; ++T) {
        AW[T] = wa[T * 64 + n * 4 + q];
        AX[T] = wx[T * 64 + n * 4 + q];
    }
#pragma unroll
    for (int T = 0; T < 2; ++T) AI[T] = wi[T * 64 + n * 4 + q];

    const int chain = bg * 16 + n;
    const float* xb = inp + tau0 * 1024 + chain * 8;
    float2 xvH = *reinterpret_cast<const float2*>(xb + 6);   // his: n=3 slot
    float2 xvI = *reinterpret_cast<const float2*>(xb);       // int: n=0 slot
    xb += 1024;

    union BU { unsigned u[4]; h8v h; };
    BU bhH; bhH.u[0] = bhH.u[1] = bhH.u[2] = bhH.u[3] = 0;   // his h
    BU bhI; bhI.u[0] = bhI.u[1] = bhI.u[2] = bhI.u[3] = 0;   // int h
    float cH[8] = {0.f, 0.f, 0.f, 0.f, 0.f, 0.f, 0.f, 0.f};
    float hH[8] = {0.f, 0.f, 0.f, 0.f, 0.f, 0.f, 0.f, 0.f};
    float cI0 = 0.f, cI1 = 0.f, ih0 = 0.f, ih1 = 0.f;

#pragma unroll 1
    for (int s = 0; s < nsteps; ++s) {
        float2 xnH = make_float2(0.f, 0.f);
        float2 xnI = make_float2(0.f, 0.f);
        if (s + 1 < nsteps) {               // wave-uniform branch
            xnH = *reinterpret_cast<const float2*>(xb + 6);
            xnI = *reinterpret_cast<const float2*>(xb);
        }
        xb += 1024;

        // his Bx: q0 lanes carry [xh, yh, 1, xh, yh, 1, xl, yl]; others 0
        BU bx;
        {
            const unsigned short xh = f2h(xvH.x), yh = f2h(xvH.y);
            const unsigned short xl = f2h(xvH.x - h2f(xh));
            const unsigned short yl = f2h(xvH.y - h2f(yh));
            bx.u[0] = ((unsigned)yh << 16) | xh;             // j1,j0
            bx.u[1] = ((unsigned)xh << 16) | H16ONE;         // j3=xh, j2=1
            bx.u[2] = (H16ONE << 16) | yh;                   // j5=1, j4=yh
            bx.u[3] = ((unsigned)yl << 16) | xl;             // j7,j6
            if (q != 0) { bx.u[0] = 0; bx.u[1] = 0; bx.u[2] = 0; bx.u[3] = 0; }
        }
        // int B x-slot: q0/q2 -> (xh,yh); q1 -> (xl,yl); q3 -> (1,1)
        {
            const unsigned short xh = f2h(xvI.x), yh = f2h(xvI.y);
            const unsigned short xl = f2h(xvI.x - h2f(xh));
            const unsigned short yl = f2h(xvI.y - h2f(yh));
            const unsigned ph = ((unsigned)yh << 16) | xh;
            const unsigned pl = ((unsigned)yl << 16) | xl;
            bhI.u[3] = (q == 3) ? ((H16ONE << 16) | H16ONE)
                                : ((q == 1) ? pl : ph);
        }

        const v4f z = {0.f, 0.f, 0.f, 0.f};

        // int: 2 MFMAs (fully independent of his chain)
        const v4f E0 = __builtin_amdgcn_mfma_f32_16x16x32_f16(AI[0], bhI.h, z, 0, 0, 0);
        const v4f E1 = __builtin_amdgcn_mfma_f32_16x16x32_f16(AI[1], bhI.h, z, 0, 0, 0);

        // his: 16 MFMAs D[T] = WhhP_T . h + WihP_T . [x;1]
        v4f D[8];
#pragma unroll
        for (int T = 0; T < 8; ++T) {
            const v4f cx = __builtin_amdgcn_mfma_f32_16x16x32_f16(AX[T], bx.h, z, 0, 0, 0);
            D[T] = __builtin_amdgcn_mfma_f32_16x16x32_f16(AW[T], bhH.h, cx, 0, 0, 0);
        }

        // int activations: units {2q, 2q+1} of chain n (7-trans form)
        lstm_unit(E0[0], E0[2], E1[0], E1[2], cI0, ih0);
        lstm_unit(E0[1], E0[3], E1[1], E1[3], cI1, ih1);

        // int h -> B-frag, in-lane (hi/lo corrected, rte-exact)
        {
            const unsigned short hh0 = f2h(ih0), hh1 = f2h(ih1);
            const unsigned short hl0 = f2h(ih0 - h2f(hh0));
            const unsigned short hl1 = f2h(ih1 - h2f(hh1));
            bhI.u[0] = ((unsigned)hh1 << 16) | hh0;
            bhI.u[1] = bhI.u[0];
            bhI.u[2] = ((unsigned)hl1 << 16) | hl0;
        }

        // his activations: 8 units (q*8+ww) of chain n (7-trans form)
#pragma unroll
        for (int hi = 0; hi < 2; ++hi) {
#pragma unroll
            for (int lo = 0; lo < 4; ++lo) {
                const int ww = hi * 4 + lo;
                lstm_unit(D[hi][lo], D[2 + hi][lo], D[4 + hi][lo],
                          D[6 + hi][lo], cH[ww], hH[ww]);
            }
        }
        // his h -> B-frag, in-lane (uncorrected: keep verified rte f2h)
#pragma unroll
        for (int d = 0; d < 4; ++d)
            bhH.u[d] = ((unsigned)f2h(hH[2 * d + 1]) << 16) | f2h(hH[2 * d]);

        xvH = xnH;
        xvI = xnI;
    }

    // ---- epilogue: combined projection, one q-reduction -----------------
    // his partial: units q*8..+7; int partial: units {2q,2q+1}
    const v4f w0a = *reinterpret_cast<const v4f*>(W_out + q * 8);
    const v4f w0b = *reinterpret_cast<const v4f*>(W_out + q * 8 + 4);
    const v4f w1a = *reinterpret_cast<const v4f*>(W_out + 40 + q * 8);
    const v4f w1b = *reinterpret_cast<const v4f*>(W_out + 40 + q * 8 + 4);
    float e0 = fmaf(W_out[33 + 2 * q], ih1, W_out[32 + 2 * q] * ih0);
    float e1 = fmaf(W_out[73 + 2 * q], ih1, W_out[72 + 2 * q] * ih0);
#pragma unroll
    for (int j = 0; j < 4; ++j) {
        e0 = fmaf(w0a[j], hH[j], fmaf(w0b[j], hH[4 + j], e0));
        e1 = fmaf(w1a[j], hH[j], fmaf(w1b[j], hH[4 + j], e1));
    }
    e0 += __shfl_xor(e0, 16); e1 += __shfl_xor(e1, 16);
    e0 += __shfl_xor(e0, 32); e1 += __shfl_xor(e1, 32);

    if (lane < 16) {
        float2 o;
        o.x = e0 + b_out[0];
        o.y = e1 + b_out[1];
        reinterpret_cast<float2*>(out)[t * 128 + chain] = o;
    }
}

extern "C" void kernel_launch(void* const* d_in, const int* in_sizes, int n_in,
                              void* d_out, int out_size, void* d_ws, size_t ws_size,
                              hipStream_t stream) {
    const float* inp     = (const float*)d_in[0];
    const float* Wih_his = (const float*)d_in[1];
    const float* Whh_his = (const float*)d_in[2];
    const float* bih_his = (const float*)d_in[3];
    const float* bhh_his = (const float*)d_in[4];
    const float* Wih_int = (const float*)d_in[5];
    const float* Whh_int = (const float*)d_in[6];
    const float* bih_int = (const float*)d_in[7];
    const float* bhh_int = (const float*)d_in[8];
    const float* W_out   = (const float*)d_in[9];
    const float* b_out   = (const float*)d_in[10];
    float* out  = (float*)d_out;
    float* ws   = (float*)d_ws;

    // pre-pass: build permuted fp16 A-frag tables (hi/lo exact splits)
    prep_kernel<<<dim3(36), dim3(256), 0, stream>>>(
        Wih_his, Whh_his, bih_his, bhh_his,
        Wih_int, Whh_int, bih_int, bhh_int, ws);

    // fused his+int LSTM: 2048 waves, 16 chains each, fence-free loop
    fusedw_kernel<<<dim3(2048), dim3(64), 0, stream>>>(
        inp, ws, W_out, b_out, out);
}